// Round 1
// baseline (209.936 us; speedup 1.0000x reference)
//
#include <hip/hip_runtime.h>

// Problem constants (from the reference)
#define S_      7
#define SS_     49
#define B_      2
#define C_      20
#define F_      30                 // B*5 + C
#define N_IMG_  16384
#define NCELL_  (N_IMG_ * SS_)     // 802816
#define COORD_  5.0f
#define NOOBJ_  0.5f

#define TPB            256
#define CELLS_PER_THR  2           // 2 cells = 240 B * 2 = 480 B = 15 float4 (16B-aligned!)
#define NBLK           (NCELL_ / (TPB * CELLS_PER_THR))   // 1568 exactly

__device__ __forceinline__ float iou8(float px, float py, float pw, float ph,
                                      float tx, float ty, float tw, float th) {
    float xA = fmaxf(px - pw * 0.5f, tx - tw * 0.5f);
    float yA = fmaxf(py - ph * 0.5f, ty - th * 0.5f);
    float xB = fminf(px + pw * 0.5f, tx + tw * 0.5f);
    float yB = fminf(py + ph * 0.5f, ty + th * 0.5f);
    float inter = fmaxf(0.f, xB - xA) * fmaxf(0.f, yB - yA);
    float areaA = pw * ph;
    float areaB = tw * th;
    return inter / (areaA + areaB - inter);
}

// All indices into p/q are compile-time constants after inlining -> stays in VGPRs.
__device__ __forceinline__ float cell_loss(const float* p, const float* q) {
    // NOOBJ * sum((p_conf - t_conf)^2) over both boxes, all cells
    float d0 = p[20] - q[20];
    float d1 = p[21] - q[21];
    float l = NOOBJ_ * (d0 * d0 + d1 * d1);

    if (q[20] > 0.f) {          // obj cell
        // class-prob term
        float sprob = 0.f;
        #pragma unroll
        for (int f = 0; f < C_; ++f) {
            float d = p[f] - q[f];
            sprob += d * d;
        }
        l += sprob;

        // responsible box via IoU argmax (first max wins -> strict >)
        float i0 = iou8(p[22], p[23], p[24], p[25], q[22], q[23], q[24], q[25]);
        float i1 = iou8(p[26], p[27], p[28], p[29], q[26], q[27], q[28], q[29]);
        bool b1 = i1 > i0;

        // confidence term for responsible box (select, not dynamic index)
        float pc = b1 ? p[21] : p[20];
        float tc = b1 ? q[21] : q[20];
        float dc = pc - tc;
        l += (1.0f - NOOBJ_) * dc * dc;

        // coord term (obj=true so tb_wh == tb[2:4])
        float pb0 = b1 ? p[26] : p[22];
        float pb1 = b1 ? p[27] : p[23];
        float pb2 = b1 ? p[28] : p[24];
        float pb3 = b1 ? p[29] : p[25];
        float tb0 = b1 ? q[26] : q[22];
        float tb1 = b1 ? q[27] : q[23];
        float tb2 = b1 ? q[28] : q[24];
        float tb3 = b1 ? q[29] : q[25];
        float bx = pb0 - tb0;
        float by = pb1 - tb1;
        float bw = sqrtf(pb2) - sqrtf(tb2);
        float bh = sqrtf(pb3) - sqrtf(tb3);
        l += COORD_ * (bx * bx + by * by + bw * bw + bh * bh);
    }
    return l;
}

__global__ __launch_bounds__(TPB, 3) void mploss_kernel(
        const float* __restrict__ preds,
        const float* __restrict__ targets,
        float* __restrict__ out) {
    __shared__ float s_red[TPB / 64];

    const int tid  = threadIdx.x;
    const int lane = tid & 63;
    const int wave = tid >> 6;

    // Thread owns 2 consecutive cells = 480 B = 15 float4 per array.
    const long pair = (long)blockIdx.x * TPB + tid;
    const float4* p4 = (const float4*)preds   + pair * 15;
    const float4* t4 = (const float4*)targets + pair * 15;

    // Issue all 30 independent 16B loads up front; compiler inserts counted
    // waitcnts. ~120 data VGPRs, no LDS staging, no block barrier.
    union { float4 v[15]; float f[60]; } P, T;
    #pragma unroll
    for (int i = 0; i < 15; ++i) P.v[i] = p4[i];
    #pragma unroll
    for (int i = 0; i < 15; ++i) T.v[i] = t4[i];

    float l = cell_loss(P.f,      T.f)
            + cell_loss(P.f + 30, T.f + 30);

    // wave (64-lane) shuffle reduction
    #pragma unroll
    for (int off = 32; off > 0; off >>= 1)
        l += __shfl_down(l, off, 64);

    if (lane == 0) s_red[wave] = l;
    __syncthreads();
    if (tid == 0) {
        float tot = s_red[0] + s_red[1] + s_red[2] + s_red[3];
        atomicAdd(out, tot * (1.0f / (float)N_IMG_));
    }
}

extern "C" void kernel_launch(void* const* d_in, const int* in_sizes, int n_in,
                              void* d_out, int out_size, void* d_ws, size_t ws_size,
                              hipStream_t stream) {
    const float* preds   = (const float*)d_in[0];
    const float* targets = (const float*)d_in[1];
    float* out = (float*)d_out;

    // d_out is poisoned 0xAA before every launch; zero it (graph-capture safe)
    hipMemsetAsync(out, 0, sizeof(float) * (size_t)out_size, stream);

    mploss_kernel<<<NBLK, TPB, 0, stream>>>(preds, targets, out);
}